// Round 7
// baseline (15477.585 us; speedup 1.0000x reference)
//
#include <hip/hip_runtime.h>

#define TL 2048

typedef __attribute__((ext_vector_type(8))) short bfx8;
typedef __attribute__((ext_vector_type(4))) float fx4;

__device__ __forceinline__ float sigf(float x){ return __builtin_amdgcn_rcpf(1.0f + __expf(-x)); }
__device__ __forceinline__ float tanhff(float x){ return fmaf(2.0f, sigf(2.0f*x), -1.0f); }

template<int CTRL>
__device__ __forceinline__ float dpp_xadd(float v){
  int s = __builtin_amdgcn_update_dpp(0, __float_as_int(v), CTRL, 0xF, 0xF, true);
  return v + __int_as_float(s);
}
__device__ __forceinline__ float swz4_add(float v){
  int s = __builtin_amdgcn_ds_swizzle(__float_as_int(v), 0x101F);
  return v + __int_as_float(s);
}
__device__ __forceinline__ float bperm(float v, int srclane){
  return __int_as_float(__builtin_amdgcn_ds_bpermute(srclane << 2, __float_as_int(v)));
}
__device__ __forceinline__ unsigned short f2bf(float f){   // RNE fp32->bf16
  unsigned int u = __float_as_uint(f);
  u += 0x7fffu + ((u >> 16) & 1u);
  return (unsigned short)(u >> 16);
}
__device__ __forceinline__ float bf2f(unsigned short h){ return __uint_as_float(((unsigned)h) << 16); }
__device__ __forceinline__ float dot4(float4 a, float4 b, float acc){
  acc = fmaf(a.x, b.x, acc); acc = fmaf(a.y, b.y, acc);
  acc = fmaf(a.z, b.z, acc); acc = fmaf(a.w, b.w, acc);
  return acc;
}
// LDS-only barrier: do NOT drain vmcnt (global stores stay in flight).
__device__ __forceinline__ void barrier_lgkm(){
  asm volatile("s_waitcnt lgkmcnt(0)\ns_barrier" ::: "memory");
}
__device__ __forceinline__ void wait_lgkm(){ asm volatile("s_waitcnt lgkmcnt(0)" ::: "memory"); }
__device__ __forceinline__ bfx8 pack8hi(const float* p){
  float4 a = *(const float4*)p, b = *(const float4*)(p + 4);
  bfx8 r;
  r[0]=(short)f2bf(a.x); r[1]=(short)f2bf(a.y); r[2]=(short)f2bf(a.z); r[3]=(short)f2bf(a.w);
  r[4]=(short)f2bf(b.x); r[5]=(short)f2bf(b.y); r[6]=(short)f2bf(b.z); r[7]=(short)f2bf(b.w);
  return r;
}
__device__ __forceinline__ bfx8 pack8lo(const float* p){
  float4 a = *(const float4*)p, b = *(const float4*)(p + 4);
  bfx8 r;
  const float* e = &a.x;
  #pragma unroll
  for (int i = 0; i < 4; ++i){ float hi = bf2f(f2bf(e[i])); r[i] = (short)f2bf(e[i] - hi); }
  const float* g = &b.x;
  #pragma unroll
  for (int i = 0; i < 4; ++i){ float hi = bf2f(f2bf(g[i])); r[4+i] = (short)f2bf(g[i] - hi); }
  return r;
}
__device__ __forceinline__ bfx8 pack8(const float* p){ return pack8hi(p); }

// Roles per launch: [0,nL1) L1-scan (MFMA rec, MB=4, hi/lo h);
// [nL1,nL1+nL2) L2-scan (round-4 proven: VALU rec + MFMA proj lookahead);
// rest L3-scan (round-4 proven: wave-pair, MFMA proj, T-mean to sums).
__global__ __launch_bounds__(512) void mega_kernel(
    int nL1, int nL2, int nL3, int cb1, int cb2, int cb3, int p1, int p2, int p3,
    const float* __restrict__ x,
    const float* __restrict__ Wih1, const float* __restrict__ Whh1,
    const float* __restrict__ bih1, const float* __restrict__ bhh1,
    const float* __restrict__ Wih2, const float* __restrict__ Whh2,
    const float* __restrict__ bih2, const float* __restrict__ bhh2,
    const float* __restrict__ Wih3, const float* __restrict__ Whh3,
    const float* __restrict__ bih3, const float* __restrict__ bhh3,
    unsigned short* __restrict__ h1r0, unsigned short* __restrict__ h1r1,
    unsigned short* __restrict__ o2r0, unsigned short* __restrict__ o2r1,
    float* __restrict__ sums)
{
  __shared__ __align__(16) unsigned char smem[34816];
  const int tid  = threadIdx.x;
  const int bid  = blockIdx.x;
  const int lane = tid & 63;
  const int wv   = tid >> 6;

  if (bid < nL1){
    // ========== L1 (NEW): H=128, MB=4, one dir. MFMA rec, h carried hi+lo. ==
    const int bq = bid >> 1, dir = bid & 1;
    unsigned short* h1o = p1 ? h1r1 : h1r0;
    const int r = lane >> 4, c = lane & 15;

    // A = Whh1 split hi/lo. wave wv: tile {8j+wv} = gate j, units [16wv,16wv+16)
    bfx8 Ahi[4][4], Alo[4][4];
    {
      const float* WhA = Whh1 + dir * 65536;
      #pragma unroll
      for (int j = 0; j < 4; ++j){
        const float* rp = WhA + ((8*j + wv)*16 + c) * 128 + 8*r;
        #pragma unroll
        for (int f = 0; f < 4; ++f){ Ahi[j][f] = pack8hi(rp + 32*f); Alo[j][f] = pack8lo(rp + 32*f); }
      }
    }
    const int pb = r, ul = c, unit = 16*wv + ul;   // pointwise: (batch pb, unit)
    float xwA[4], xwB[4], bs[4];
    #pragma unroll
    for (int j = 0; j < 4; ++j){
      const int row = 128*j + unit;
      xwA[j] = Wih1[dir*1024 + row*2];
      xwB[j] = Wih1[dir*1024 + row*2 + 1];
      bs[j]  = bih1[dir*512 + row] + bhh1[dir*512 + row];
    }
    unsigned short* hbhi = (unsigned short*)smem;          // [2][4][136]
    unsigned short* hblo = hbhi + 1088;                    // [2][4][136]
    float4* gw = (float4*)(smem + 4352) + wv * 68;         // per-wave gate dump
    float2* xlds = (float2*)(smem + 13056);                // [16][4]
    for (int i = tid; i < 1088; i += 512) ((unsigned int*)smem)[i] = 0u;
    const int cloc = 4*bq + pb;
    unsigned short* h1p = h1o + ((size_t)cloc*TL + (dir ? TL-1 : 0))*256 + dir*128 + unit;
    const int hstep = dir ? -256 : 256;
    const int xs_ = lane >> 2, xb_ = lane & 3;
    const float* xgp = x + ((size_t)(cb1 + 4*bq + xb_) * TL) * 2;
    float2 xr = make_float2(0.f, 0.f);
    if (wv == 7){
      const int tt0 = dir ? (TL-1-xs_) : xs_;
      xr = *(const float2*)(xgp + tt0*2);
    }
    __syncthreads();
    if (wv == 7) xlds[xs_*4 + xb_] = xr;
    __syncthreads();

    float cst = 0.0f;
    for (int blk = 0; blk < 128; ++blk){
      if (wv == 7 && blk + 1 < 128){
        const int tn = 16*(blk+1) + xs_;
        const int ttn = dir ? (TL-1-tn) : tn;
        xr = *(const float2*)(xgp + ttn*2);
      }
      for (int s = 0; s < 16; ++s){
        const int par = s & 1, nxt = par ^ 1;
        const int brow = (par*4 + (c & 3))*136;
        bfx8 Bh[4], Bl[4];
        #pragma unroll
        for (int f = 0; f < 4; ++f){
          uint4 th = *(const uint4*)(hbhi + brow + 32*f + 8*r);
          uint4 tl = *(const uint4*)(hblo + brow + 32*f + 8*r);
          __builtin_memcpy(&Bh[f], &th, 16);
          __builtin_memcpy(&Bl[f], &tl, 16);
        }
        fx4 acc[4];
        #pragma unroll
        for (int j = 0; j < 4; ++j){
          fx4 a = {0.f,0.f,0.f,0.f};
          #pragma unroll
          for (int f = 0; f < 4; ++f) a = __builtin_amdgcn_mfma_f32_16x16x32_bf16(Ahi[j][f], Bh[f], a, 0,0,0);
          #pragma unroll
          for (int f = 0; f < 4; ++f) a = __builtin_amdgcn_mfma_f32_16x16x32_bf16(Ahi[j][f], Bl[f], a, 0,0,0);
          #pragma unroll
          for (int f = 0; f < 4; ++f) a = __builtin_amdgcn_mfma_f32_16x16x32_bf16(Alo[j][f], Bh[f], a, 0,0,0);
          acc[j] = a;
        }
        if (c < 4){
          #pragma unroll
          for (int reg = 0; reg < 4; ++reg)
            gw[c*17 + 4*r + reg] = make_float4(acc[0][reg], acc[1][reg], acc[2][reg], acc[3][reg]);
        }
        wait_lgkm();
        const float4 g4 = gw[pb*17 + ul];
        const float2 xv = xlds[s*4 + pb];
        const float pre0 = g4.x + fmaf(xwA[0], xv.x, fmaf(xwB[0], xv.y, bs[0]));
        const float pre1 = g4.y + fmaf(xwA[1], xv.x, fmaf(xwB[1], xv.y, bs[1]));
        const float pre2 = g4.z + fmaf(xwA[2], xv.x, fmaf(xwB[2], xv.y, bs[2]));
        const float pre3 = g4.w + fmaf(xwA[3], xv.x, fmaf(xwB[3], xv.y, bs[3]));
        const float ig = sigf(pre0), fg = sigf(pre1), gg = tanhff(pre2), og = sigf(pre3);
        cst = fmaf(fg, cst, ig*gg);
        const float h = og * tanhff(cst);
        const unsigned short hhi = f2bf(h);
        const unsigned short hlo = f2bf(h - bf2f(hhi));
        hbhi[(nxt*4 + pb)*136 + unit] = hhi;
        hblo[(nxt*4 + pb)*136 + unit] = hlo;
        *h1p = hhi; h1p += hstep;
        barrier_lgkm();
      }
      if (wv == 7 && blk + 1 < 128) xlds[xs_*4 + xb_] = xr;
      barrier_lgkm();
    }

  } else if (bid < nL1 + nL2){
    // ========== L2 (round-4 proven): H=64; proj (K=256) via MFMA lookahead. ==
    const int i2 = bid - nL1;
    const int bloc = i2 >> 1, dir = i2 & 1;
    const unsigned short* h1i = (p2 ? h1r1 : h1r0) + (size_t)bloc * TL * 256;
    unsigned short* o2o = p2 ? o2r1 : o2r0;
    const int kc = tid & 7, u = tid >> 3;

    float4 wr[4][2]; float bs[4];
    const float* WR = Whh2 + dir * 16384;
    #pragma unroll
    for (int tgt = 0; tgt < 4; ++tgt){
      const int row = tgt * 64 + u;
      wr[tgt][0] = *(const float4*)(WR + row * 64 + kc * 8);
      wr[tgt][1] = *(const float4*)(WR + row * 64 + kc * 8 + 4);
      bs[tgt] = bih2[dir * 256 + row] + bhh2[dir * 256 + row];
    }
    bfx8 Bf[2][8];
    const float* WP = Wih2 + dir * 65536;
    #pragma unroll
    for (int ntl = 0; ntl < 2; ++ntl){
      const int n = (2 * wv + ntl) * 16 + (lane & 15);
      #pragma unroll
      for (int Kf = 0; Kf < 8; ++Kf)
        Bf[ntl][Kf] = pack8(WP + n * 256 + Kf * 32 + (lane >> 4) * 8);
    }
    float* xs  = (float*)smem;                   // 2 bufs x 16 x 258 f
    float* h2b = (float*)(smem + 33024);         // 2 x 64 f
    if (tid < 64){ h2b[tid] = 0.0f; h2b[64 + tid] = 0.0f; }

    auto loadA = [&](int blk, uint4* a8){
      const int m  = lane & 15;
      const int pt = dir ? (TL - 1 - (blk * 16 + m)) : (blk * 16 + m);
      const unsigned short* base = h1i + (size_t)pt * 256 + (lane >> 4) * 8;
      #pragma unroll
      for (int Kf = 0; Kf < 8; ++Kf) a8[Kf] = *(const uint4*)(base + Kf * 32);
    };
    auto domfma = [&](uint4* a8, int buf){
      fx4 acc0 = {0.f,0.f,0.f,0.f}, acc1 = {0.f,0.f,0.f,0.f};
      #pragma unroll
      for (int Kf = 0; Kf < 8; ++Kf){
        bfx8 av; __builtin_memcpy(&av, &a8[Kf], 16);
        acc0 = __builtin_amdgcn_mfma_f32_16x16x32_bf16(av, Bf[0][Kf], acc0, 0, 0, 0);
        acc1 = __builtin_amdgcn_mfma_f32_16x16x32_bf16(av, Bf[1][Kf], acc1, 0, 0, 0);
      }
      const int c0 = (2 * wv) * 16 + (lane & 15);
      #pragma unroll
      for (int rr = 0; rr < 4; ++rr){
        const int row = (lane >> 4) * 4 + rr;
        xs[buf * 4128 + row * 258 + c0]      = acc0[rr];
        xs[buf * 4128 + row * 258 + c0 + 16] = acc1[rr];
      }
    };

    uint4 a8[8];
    loadA(0, a8); domfma(a8, 0);
    loadA(1, a8); domfma(a8, 1);
    __syncthreads();

    float cst = 0.0f;
    uint4 pf[8];
    for (int B = 0; B < 128; ++B){
      if (B + 2 < 128) loadA(B + 2, pf);
      const int pb = B & 1;
      for (int s = 0; s < 16; ++s){
        const int t  = B * 16 + s;
        const int tt = dir ? (TL - 1 - t) : t;
        const int cur = t & 1;
        const float4* hv4 = (const float4*)(h2b + cur * 64) + kc * 2;
        const float4 hA = hv4[0], hB = hv4[1];
        float a0 = dot4(wr[0][1], hB, dot4(wr[0][0], hA, 0.f));
        float a1 = dot4(wr[1][1], hB, dot4(wr[1][0], hA, 0.f));
        float a2 = dot4(wr[2][1], hB, dot4(wr[2][0], hA, 0.f));
        float a3 = dot4(wr[3][1], hB, dot4(wr[3][0], hA, 0.f));
        a0 = swz4_add(dpp_xadd<0x4E>(dpp_xadd<0xB1>(a0)));
        a1 = swz4_add(dpp_xadd<0x4E>(dpp_xadd<0xB1>(a1)));
        a2 = swz4_add(dpp_xadd<0x4E>(dpp_xadd<0xB1>(a2)));
        a3 = swz4_add(dpp_xadd<0x4E>(dpp_xadd<0xB1>(a3)));
        if (kc == 0){
          const float* xr = xs + pb * 4128 + s * 258 + u;
          const float ig = sigf(a0 + xr[0]   + bs[0]);
          const float fg = sigf(a1 + xr[64]  + bs[1]);
          const float gg = tanhff(a2 + xr[128] + bs[2]);
          const float og = sigf(a3 + xr[192] + bs[3]);
          cst = fmaf(fg, cst, ig * gg);
          const float h = og * tanhff(cst);
          h2b[(cur ^ 1) * 64 + u] = h;
          o2o[((size_t)bloc * TL + tt) * 128 + dir * 64 + u] = f2bf(h);
        }
        barrier_lgkm();
      }
      if (B + 2 < 128) domfma(pf, pb);
    }

  } else {
    // ========== L3 (round-4 proven): H=16; MFMA proj; T-mean to sums. =======
    const int i3 = bid - nL1 - nL2;
    const int dir = i3 & 1, q4 = i3 >> 1;
    const int grp = tid >> 7, lt = tid & 127;
    const int bloc = q4 * 4 + grp;
    const unsigned short* o2i = (p3 ? o2r1 : o2r0) + (size_t)bloc * TL * 128;
    const int u = lt >> 3, j = lt & 7, gt = j >> 1, kc = j & 1;
    const int half = wv & 1;

    const float* WR = Whh3 + dir * 1024;
    const int r = gt * 16 + u;
    const float4 wr0 = *(const float4*)(WR + r * 16 + kc * 8);
    const float4 wr1 = *(const float4*)(WR + r * 16 + kc * 8 + 4);
    const float bsv = bih3[dir * 64 + r] + bhh3[dir * 64 + r];
    const int ubase = lane & ~7;
    const float bI = bperm(bsv, ubase + 0), bF = bperm(bsv, ubase + 2);
    const float bG = bperm(bsv, ubase + 4), bO = bperm(bsv, ubase + 6);

    bfx8 Bf[2][4];
    const float* WP = Wih3 + dir * 8192;     // (64,128)
    #pragma unroll
    for (int ntl = 0; ntl < 2; ++ntl){
      const int n = (2 * half + ntl) * 16 + (lane & 15);
      #pragma unroll
      for (int Kf = 0; Kf < 4; ++Kf)
        Bf[ntl][Kf] = pack8(WP + n * 128 + Kf * 32 + (lane >> 4) * 8);
    }
    float* xs  = (float*)smem + grp * 2112;  // per chain: 2 bufs x 16 x 66 f
    float* h3b = (float*)(smem + 33792) + grp * 32;
    if (lt < 32) h3b[lt] = 0.0f;

    auto loadA3 = [&](int blk, uint4* a4){
      const int m  = lane & 15;
      const int pt = dir ? (TL - 1 - (blk * 16 + m)) : (blk * 16 + m);
      const unsigned short* base = o2i + (size_t)pt * 128 + (lane >> 4) * 8;
      #pragma unroll
      for (int Kf = 0; Kf < 4; ++Kf) a4[Kf] = *(const uint4*)(base + Kf * 32);
    };
    auto domfma3 = [&](uint4* a4, int buf){
      fx4 acc0 = {0.f,0.f,0.f,0.f}, acc1 = {0.f,0.f,0.f,0.f};
      #pragma unroll
      for (int Kf = 0; Kf < 4; ++Kf){
        bfx8 av; __builtin_memcpy(&av, &a4[Kf], 16);
        acc0 = __builtin_amdgcn_mfma_f32_16x16x32_bf16(av, Bf[0][Kf], acc0, 0, 0, 0);
        acc1 = __builtin_amdgcn_mfma_f32_16x16x32_bf16(av, Bf[1][Kf], acc1, 0, 0, 0);
      }
      const int c0 = (2 * half) * 16 + (lane & 15);
      #pragma unroll
      for (int rr = 0; rr < 4; ++rr){
        const int row = (lane >> 4) * 4 + rr;
        xs[buf * 1056 + row * 66 + c0]      = acc0[rr];
        xs[buf * 1056 + row * 66 + c0 + 16] = acc1[rr];
      }
    };

    uint4 a4[4];
    loadA3(0, a4); domfma3(a4, 0);
    loadA3(1, a4); domfma3(a4, 1);
    __syncthreads();

    float cst = 0.0f, msum = 0.0f;
    uint4 pf[4];
    for (int B = 0; B < 128; ++B){
      if (B + 2 < 128) loadA3(B + 2, pf);
      const int pb = B & 1;
      for (int s = 0; s < 16; ++s){
        const int t = B * 16 + s;
        const int cur = t & 1;
        const float4* h3p = (const float4*)(h3b + cur * 16 + kc * 8);
        float acc = dot4(wr1, h3p[1], dot4(wr0, h3p[0], 0.f));
        acc = dpp_xadd<0xB1>(acc);
        const float gI = bperm(acc, ubase + 0), gF = bperm(acc, ubase + 2);
        const float gG = bperm(acc, ubase + 4), gO = bperm(acc, ubase + 6);
        if (j == 0){
          const float* xr = xs + pb * 1056 + s * 66 + u;
          const float ig = sigf(gI + bI + xr[0]);
          const float fg = sigf(gF + bF + xr[16]);
          const float gg = tanhff(gG + bG + xr[32]);
          const float og = sigf(gO + bO + xr[48]);
          cst = fmaf(fg, cst, ig * gg);
          const float h = og * tanhff(cst);
          h3b[(cur ^ 1) * 16 + u] = h;
          msum += h;
        }
        barrier_lgkm();
      }
      if (B + 2 < 128) domfma3(pf, pb);
    }
    if (j == 0) sums[(size_t)(cb3 + bloc) * 32 + dir * 16 + u] = msum;
  }
}

// ---------------- head: mean (pre-summed) + MLP, one 64-thr WG per batch
__global__ __launch_bounds__(64) void head_kernel(
    const float* __restrict__ sums,
    const float* __restrict__ hW1, const float* __restrict__ hb1,
    const float* __restrict__ hW2, const float* __restrict__ hb2,
    const float* __restrict__ hW3, const float* __restrict__ hb3,
    float* __restrict__ out)
{
  __shared__ float m[32], h1s[64], h2s[16];
  const int tid = threadIdx.x, b = blockIdx.x;
  if (tid < 32) m[tid] = sums[b * 32 + tid] * (1.0f / 2048.0f);
  __syncthreads();
  {
    float a = hb1[tid];
    #pragma unroll
    for (int k = 0; k < 32; ++k) a = fmaf(m[k], hW1[tid * 32 + k], a);
    h1s[tid] = fmaxf(a, 0.0f);
  }
  __syncthreads();
  if (tid < 16){
    float a = hb2[tid];
    #pragma unroll
    for (int k = 0; k < 64; ++k) a = fmaf(h1s[k], hW2[tid * 64 + k], a);
    h2s[tid] = fmaxf(a, 0.0f);
  }
  __syncthreads();
  if (tid < 20){
    float a = hb3[tid];
    #pragma unroll
    for (int k = 0; k < 16; ++k) a = fmaf(h2s[k], hW3[tid * 16 + k], a);
    out[b * 20 + tid] = a;
  }
}

extern "C" void kernel_launch(void* const* d_in, const int* in_sizes, int n_in,
                              void* d_out, int out_size, void* d_ws, size_t ws_size,
                              hipStream_t stream) {
  (void)in_sizes; (void)n_in; (void)out_size; (void)ws_size;
  const float* x    = (const float*)d_in[0];
  const float* Wih1 = (const float*)d_in[1];
  const float* Whh1 = (const float*)d_in[2];
  const float* bih1 = (const float*)d_in[3];
  const float* bhh1 = (const float*)d_in[4];
  const float* Wih2 = (const float*)d_in[5];
  const float* Whh2 = (const float*)d_in[6];
  const float* bih2 = (const float*)d_in[7];
  const float* bhh2 = (const float*)d_in[8];
  const float* Wih3 = (const float*)d_in[9];
  const float* Whh3 = (const float*)d_in[10];
  const float* bih3 = (const float*)d_in[11];
  const float* bhh3 = (const float*)d_in[12];
  const float* hW1  = (const float*)d_in[13];
  const float* hb1  = (const float*)d_in[14];
  const float* hW2  = (const float*)d_in[15];
  const float* hb2  = (const float*)d_in[16];
  const float* hW3  = (const float*)d_in[17];
  const float* hb3  = (const float*)d_in[18];

  // Workspace (151 MB + sums; >=167.8 MB proven available by round-2's BC=32):
  // h1 rings (48,2048,256) bf16 x2 | o2 rings (48,2048,128) bf16 x2 | sums f32
  unsigned short* h1r0 = (unsigned short*)d_ws;
  unsigned short* h1r1 = h1r0 + (size_t)48 * TL * 256;
  unsigned short* o2r0 = (unsigned short*)((unsigned char*)d_ws + 100663296u);
  unsigned short* o2r1 = o2r0 + (size_t)48 * TL * 128;
  float* sums = (float*)((unsigned char*)d_ws + 150994944u);

  const int nbs[6] = {48, 48, 48, 48, 48, 16};
  const int cbs[6] = {0, 48, 96, 144, 192, 240};
  for (int k = 0; k < 8; ++k){
    const int a1 = (k < 6) ? nbs[k] : 0;
    const int a2 = (k >= 1 && k < 7) ? nbs[k - 1] : 0;
    const int a3 = (k >= 2) ? nbs[k - 2] : 0;
    const int nL1 = (a1 / 4) * 2, nL2 = 2 * a2, nL3 = a3 / 2;
    mega_kernel<<<dim3(nL1 + nL2 + nL3), dim3(512), 0, stream>>>(
        nL1, nL2, nL3,
        (k < 6) ? cbs[k] : 0, (k >= 1 && k < 7) ? cbs[k - 1] : 0,
        (k >= 2) ? cbs[k - 2] : 0,
        k & 1, (k + 1) & 1, k & 1,
        x, Wih1, Whh1, bih1, bhh1, Wih2, Whh2, bih2, bhh2,
        Wih3, Whh3, bih3, bhh3, h1r0, h1r1, o2r0, o2r1, sums);
  }
  head_kernel<<<dim3(256), dim3(64), 0, stream>>>(
      sums, hW1, hb1, hW2, hb2, hW3, hb3, (float*)d_out);
}